// Round 6
// baseline (510.643 us; speedup 1.0000x reference)
//
#include <hip/hip_runtime.h>
#include <math.h>

// ---------------------------------------------------------------------------
// QuantumGenerator, R1-streaming structure + last-block stats fold.
// Measured ranking: R1 streaming (44us kernels) << R3 atomic-fold (73us)
// < R5 1-wave/SIMD recompute (81us). R1 = ~24us memory + ~20us of 10 serial
// launch gaps. This round removes 4 stats launches: producer's LAST block
// (threadfence + counter, rocPRIM pattern) reduces the per-slot partials and
// writes next layer's BN scale/shift. 6 launches total.
// ---------------------------------------------------------------------------

#define NB 1024

__global__ __launch_bounds__(256) void build_V_kernel(
    const float* __restrict__ w1, const float* __restrict__ w2,
    const float* __restrict__ w3, const float* __restrict__ w4,
    float* __restrict__ V, int* __restrict__ cnts)
{
    int t = blockIdx.x * blockDim.x + threadIdx.x;
    if (t < 4) cnts[t] = 0;                  // re-arm last-block counters
    if (t >= 340) return;
    const float* w; float* vout;
    if (t < 256)      { w = w1 + t*18;        vout = V + t*16; }
    else if (t < 320) { w = w2 + (t-256)*18;  vout = V + 4096 + (t-256)*16; }
    else if (t < 336) { w = w3 + (t-320)*18;  vout = V + 5120 + (t-320)*16; }
    else              { w = w4 + (t-336)*18;  vout = V + 5376 + (t-336)*16; }
    const int perm[8] = {0,5,7,2,3,6,4,1};   // CNOT ring row permutation
    float U[8][8];
    #pragma unroll
    for (int i=0;i<8;i++)
        #pragma unroll
        for (int jj=0;jj<8;jj++) U[i][jj] = (i==jj) ? 1.0f : 0.0f;
    for (int l=0;l<6;l++){
        float c0 = cosf(0.5f*w[l*3+0]), s0 = sinf(0.5f*w[l*3+0]);
        float c1 = cosf(0.5f*w[l*3+1]), s1 = sinf(0.5f*w[l*3+1]);
        float c2 = cosf(0.5f*w[l*3+2]), s2 = sinf(0.5f*w[l*3+2]);
        #pragma unroll
        for (int col=0; col<8; col++){
            float v[8];
            #pragma unroll
            for (int r=0;r<8;r++) v[r] = U[r][col];
            #pragma unroll
            for (int bb=0;bb<8;bb+=2){ float x=v[bb], y=v[bb+1]; v[bb]=c2*x-s2*y; v[bb+1]=s2*x+c2*y; }
            #pragma unroll
            for (int g=0;g<8;g+=4)
                #pragma unroll
                for (int i=0;i<2;i++){ int a=g+i, bq=g+i+2; float x=v[a], y=v[bq]; v[a]=c1*x-s1*y; v[bq]=s1*x+c1*y; }
            #pragma unroll
            for (int i=0;i<4;i++){ float x=v[i], y=v[i+4]; v[i]=c0*x-s0*y; v[i+4]=s0*x+c0*y; }
            #pragma unroll
            for (int r=0;r<8;r++) U[perm[r]][col] = v[r];
        }
    }
    #pragma unroll
    for (int jj=0;jj<4;jj++)
        #pragma unroll
        for (int k=0;k<4;k++) vout[jj*4+k] = U[jj][k];
}

// One thread = one (batch, channel, patch); NB blocks x 256 thr x 4 iters.
// BN of the input uses precomputed scPrev/shPrev. Output per-channel partial
// sums -> psum/pssq (plain stores); LAST block reduces them into next BN's
// scale/shift (gammaN/betaN folded).
template<int C, int H, int W, bool BN>
__global__ __launch_bounds__(256) void qcnn_kernel(
    const float* __restrict__ x, const float* __restrict__ V,
    const float* __restrict__ scPrev, const float* __restrict__ shPrev,
    float* __restrict__ out, float* __restrict__ psum, float* __restrict__ pssq,
    const float* __restrict__ gammaN, const float* __restrict__ betaN,
    float invN, float* __restrict__ scaleN, float* __restrict__ shiftN,
    int* __restrict__ cnt)
{
    constexpr int HW  = H*W;
    constexpr int P   = HW/4;                 // patches/channel: 4,16,64,256
    constexpr int OW  = W/2;
    constexpr int LP  = (P==4)?2:(P==16)?4:(P==64)?6:8;
    constexpr int LOW = (OW==2)?1:(OW==4)?2:(OW==8)?3:4;
    constexpr int OC  = C/4;                  // BN channels of the OUTPUT
    constexpr int OCB = (64/P) < 1 ? 1 : (64/P);   // out-ch bins/block: 16,4,1,1
    constexpr int G   = (4*P < 64) ? 4*P : 64;     // lanes per out-ch
    constexpr int DIV   = OC/OCB < 1 ? 1 : OC/OCB; // 4,4,4,1
    constexpr int NSLOT = NB/DIV;                  // 256,256,256,1024
    constexpr int TPO   = (256/OC < 64) ? 256/OC : 64;  // tail threads/oc

    __shared__ float sBin[2*OCB];
    __shared__ int lastFlag;
    const int tid = threadIdx.x;
    if (tid < 2*OCB) sBin[tid] = 0.0f;
    __syncthreads();

    const int r0  = (blockIdx.x & 3) * 256;   // per-batch flat r-range
    const int oc0 = r0 >> (LP+2);

    for (int it=0; it<4; ++it){
        int tg = (it<<18) + (blockIdx.x<<8) + tid;   // NB*256 = 2^18
        int b  = tg >> 10;
        int r  = tg & 1023;
        int c  = r >> LP;
        int p  = r & (P-1);
        int oh = p >> LOW;
        int ow = p & (OW-1);
        const float* xb = x + ((size_t)b<<12) + c*HW + (oh*2)*W + (ow*2);
        float2 t0 = *reinterpret_cast<const float2*>(xb);
        float2 t1 = *reinterpret_cast<const float2*>(xb + W);
        float x0=t0.x, x1=t0.y, x2=t1.x, x3=t1.y;
        if constexpr (BN){
            float sc = scPrev[c], sh = shPrev[c];
            x0 = fmaxf(fmaf(x0,sc,sh), 0.0f);
            x1 = fmaxf(fmaf(x1,sc,sh), 0.0f);
            x2 = fmaxf(fmaf(x2,sc,sh), 0.0f);
            x3 = fmaxf(fmaf(x3,sc,sh), 0.0f);
        }
        float nrm = sqrtf(x0*x0 + x1*x1 + x2*x2 + x3*x3);
        float inv = 1.0f / fmaxf(nrm, 1e-9f);
        float a0=x0*inv, a1=x1*inv, a2=x2*inv, a3=x3*inv;
        const float4* Vc = reinterpret_cast<const float4*>(V + (c<<4));
        float4 v0 = Vc[0], v1 = Vc[1], v2 = Vc[2], v3 = Vc[3];
        float q0 = v0.x*a0 + v0.y*a1 + v0.z*a2 + v0.w*a3;
        float q1 = v1.x*a0 + v1.y*a1 + v1.z*a2 + v1.w*a3;
        float q2 = v2.x*a0 + v2.y*a1 + v2.z*a2 + v2.w*a3;
        float q3 = v3.x*a0 + v3.y*a1 + v3.z*a2 + v3.w*a3;
        q0*=q0; q1*=q1; q2*=q2; q3*=q3;
        float dinv = 1.0f / fmaxf(q0+q1+q2+q3, 1e-9f);
        float d0=q0*dinv, d1=q1*dinv, d2=q2*dinv, d3=q3*dinv;
        *reinterpret_cast<float4*>(out + ((size_t)b<<12) + (r<<2)) =
            make_float4(d0,d1,d2,d3);
        float ls  = d0+d1+d2+d3;
        float lss = d0*d0 + d1*d1 + d2*d2 + d3*d3;
        #pragma unroll
        for (int off=1; off<G; off<<=1){
            ls  += __shfl_xor(ls,  off);
            lss += __shfl_xor(lss, off);
        }
        if ((tid & (G-1)) == 0){
            int ocl = (r >> (LP+2)) - oc0;
            atomicAdd(&sBin[ocl], ls);
            atomicAdd(&sBin[OCB + ocl], lss);
        }
    }
    __syncthreads();
    if (tid < OCB){
        int slot = blockIdx.x / DIV;
        psum[(oc0 + tid)*NSLOT + slot] = sBin[tid];
        pssq[(oc0 + tid)*NSLOT + slot] = sBin[OCB + tid];
    }
    // ---- last-block fold: partials -> scale/shift of the NEXT BN ----
    __threadfence();                          // release our psum stores
    __syncthreads();                          // all threads past their fence
    if (tid == 0) lastFlag = (atomicAdd(cnt, 1) == NB-1) ? 1 : 0;
    __syncthreads();
    if (lastFlag){
        __threadfence();                      // acquire others' stores
        int oc = tid / TPO;
        if (oc < OC){
            float s=0.0f, q=0.0f;
            for (int s0 = tid % TPO; s0 < NSLOT; s0 += TPO){
                s += psum[oc*NSLOT + s0];
                q += pssq[oc*NSLOT + s0];
            }
            #pragma unroll
            for (int off=1; off<TPO; off<<=1){
                s += __shfl_xor(s, off);
                q += __shfl_xor(q, off);
            }
            if ((tid % TPO) == 0){
                float mean = s*invN;
                float var  = q*invN - mean*mean;
                float r    = 1.0f / sqrtf(var + 1e-5f);
                float sc   = gammaN[oc]*r;
                scaleN[oc] = sc;
                shiftN[oc] = betaN[oc] - mean*sc;
            }
        }
    }
}

__device__ __forceinline__ float fast_tanh(float x){
    float e = __expf(2.0f*x);          // inf/0 endpoints give +/-1 correctly
    return 1.0f - 2.0f/(e + 1.0f);
}

__global__ __launch_bounds__(256) void final_kernel(
    const float* __restrict__ s4, const float* __restrict__ scf,
    const float* __restrict__ shf, float* __restrict__ out_tanh,
    float* __restrict__ out_bn)
{
    float sc = scf[0], sh = shf[0];
    int i = blockIdx.x*blockDim.x + threadIdx.x;   // 1M float4s
    float4 v = reinterpret_cast<const float4*>(s4)[i];
    float4 bn = make_float4(fmaf(v.x,sc,sh), fmaf(v.y,sc,sh),
                            fmaf(v.z,sc,sh), fmaf(v.w,sc,sh));
    reinterpret_cast<float4*>(out_bn)[i] = bn;
    reinterpret_cast<float4*>(out_tanh)[i] =
        make_float4(fast_tanh(bn.x), fast_tanh(bn.y),
                    fast_tanh(bn.z), fast_tanh(bn.w));
}

extern "C" void kernel_launch(void* const* d_in, const int* in_sizes, int n_in,
                              void* d_out, int out_size, void* d_ws, size_t ws_size,
                              hipStream_t stream)
{
    const float* z      = (const float*)d_in[0];
    const float* w1     = (const float*)d_in[1];
    const float* w2     = (const float*)d_in[2];
    const float* w3     = (const float*)d_in[3];
    const float* w4     = (const float*)d_in[4];
    const float* gamma2 = (const float*)d_in[5];
    const float* beta2  = (const float*)d_in[6];
    const float* gamma3 = (const float*)d_in[7];
    const float* beta3  = (const float*)d_in[8];
    const float* gamma4 = (const float*)d_in[9];
    const float* beta4  = (const float*)d_in[10];
    const float* gammaf = (const float*)d_in[11];
    const float* betaf  = (const float*)d_in[12];
    float* out = (float*)d_out;
    float* ws  = (float*)d_ws;

    // workspace layout (floats)
    float* V    = ws;                                    // 5440
    float* sc2  = ws + 6144;  float* sh2 = ws + 6208;    // 64 each
    float* sc3  = ws + 6272;  float* sh3 = ws + 6336;    // 16 each
    float* sc4  = ws + 6400;  float* sh4 = ws + 6464;    // 4 each
    float* scf  = ws + 6528;  float* shf = ws + 6592;    // 1 each
    int*   cnts = (int*)(ws + 6656);                     // 4 counters
    float* p1s  = ws + 8192;   float* p1q = ws + 24576;  // 64*256 each
    float* p2s  = ws + 40960;  float* p2q = ws + 45056;  // 16*256
    float* p3s  = ws + 49152;  float* p3q = ws + 50176;  // 4*256
    float* p4s  = ws + 51200;  float* p4q = ws + 52224;  // 1*1024
    float* bufA = ws + 65536;                  // 4M floats (s1, then s3)
    float* bufB = ws + 65536 + 4194304;        // 4M floats (s2)

    float* out_tanh = out;                     // output 0
    float* s4       = out + 4194304;           // output 1 (written by L4)
    float* out_bn   = out + 8388608;           // output 2

    build_V_kernel<<<2, 256, 0, stream>>>(w1, w2, w3, w4, V, cnts);

    qcnn_kernel<256,4,4,false><<<NB, 256, 0, stream>>>(
        z, V, nullptr, nullptr, bufA, p1s, p1q,
        gamma2, beta2, 1.0f/65536.0f, sc2, sh2, cnts+0);
    qcnn_kernel<64,8,8,true><<<NB, 256, 0, stream>>>(
        bufA, V+4096, sc2, sh2, bufB, p2s, p2q,
        gamma3, beta3, 1.0f/262144.0f, sc3, sh3, cnts+1);
    qcnn_kernel<16,16,16,true><<<NB, 256, 0, stream>>>(
        bufB, V+5120, sc3, sh3, bufA, p3s, p3q,
        gamma4, beta4, 1.0f/1048576.0f, sc4, sh4, cnts+2);
    qcnn_kernel<4,32,32,true><<<NB, 256, 0, stream>>>(
        bufA, V+5376, sc4, sh4, s4, p4s, p4q,
        gammaf, betaf, 1.0f/4194304.0f, scf, shf, cnts+3);

    final_kernel<<<4096, 256, 0, stream>>>(s4, scf, shf, out_tanh, out_bn);
}